// Round 10
// baseline (429.097 us; speedup 1.0000x reference)
//
#include <hip/hip_runtime.h>
#include <hip/hip_bf16.h>
#include <stdint.h>

#define NT 2048
#define DM 1024
#define DFF 2048
#define NE 8
#define NASSIGN (NT*2)
#define CAPROWS (NASSIGN+128)
#define MAXTILES 40
#define BK 32   // k-chunk per LDS tile, in ushorts (64B rows)

typedef __attribute__((ext_vector_type(4))) float f32x4;
typedef __attribute__((ext_vector_type(8))) short bf16x8;

// async global->LDS, 16B per lane; LDS dest = wave-uniform base + lane*16
#define GLOAD16(gptr, lptr) __builtin_amdgcn_global_load_lds( \
    (const __attribute__((address_space(1))) void*)(gptr), \
    (__attribute__((address_space(3))) void*)(lptr), 16, 0, 0)

__device__ __forceinline__ ushort f2bf(float f) {
  union { float f; uint32_t u; } v; v.f = f;
  uint32_t u = v.u;
  return (ushort)((u + 0x7FFFu + ((u >> 16) & 1u)) >> 16);
}
__device__ __forceinline__ float bf2f(ushort h) {
  union { uint32_t u; float f; } v; v.u = ((uint32_t)h) << 16;
  return v.f;
}

// ---------------- router: one wave per token (no atomics) ----------------
__global__ __launch_bounds__(256) void k_router(const float* __restrict__ x,
    const float* __restrict__ rw, int* __restrict__ tok_e, float* __restrict__ tok_p) {
  __shared__ float srw[NE*DM];
  int tid = threadIdx.x;
  #pragma unroll
  for (int i = 0; i < NE*DM/256; i++) srw[tid + i*256] = rw[tid + i*256];
  __syncthreads();
  int lane = tid & 63;
  int t = blockIdx.x*4 + (tid >> 6);
  const float* xr = x + (size_t)t*DM;
  float acc[NE];
  #pragma unroll
  for (int e = 0; e < NE; e++) acc[e] = 0.f;
  for (int i = lane; i < DM; i += 64) {
    float xv = xr[i];
    #pragma unroll
    for (int e = 0; e < NE; e++) acc[e] = fmaf(xv, srw[e*DM + i], acc[e]);
  }
  #pragma unroll
  for (int e = 0; e < NE; e++) {
    float v = acc[e];
    #pragma unroll
    for (int o = 32; o > 0; o >>= 1) v += __shfl_xor(v, o);
    acc[e] = v;
  }
  float mx = acc[0];
  #pragma unroll
  for (int e = 1; e < NE; e++) mx = fmaxf(mx, acc[e]);
  float p[NE]; float s = 0.f;
  #pragma unroll
  for (int e = 0; e < NE; e++) { p[e] = __expf(acc[e]-mx); s += p[e]; }
  int e1 = 0; float b1 = p[0];
  #pragma unroll
  for (int e = 1; e < NE; e++) if (p[e] > b1) { b1 = p[e]; e1 = e; }
  int e2 = -1; float b2 = -1.f;
  #pragma unroll
  for (int e = 0; e < NE; e++) if (e != e1 && p[e] > b2) { b2 = p[e]; e2 = e; }
  if (lane == 0) {
    tok_e[2*t] = e1; tok_e[2*t+1] = e2;
    float inv = 1.f/s;
    tok_p[2*t] = b1*inv; tok_p[2*t+1] = b2*inv;
  }
}

// ---------------- count: deterministic within-chunk ranks, no atomics -------
__global__ __launch_bounds__(256) void k_count(const int* __restrict__ tok_e,
    int* __restrict__ rnk, int* __restrict__ chunk_cnt) {
  __shared__ int wcnt[4][NE];
  __shared__ int woff[4][NE];
  int tid = threadIdx.x, lane = tid & 63, wv = tid >> 6;
  int t = blockIdx.x*256 + tid;
  int e1 = tok_e[2*t], e2 = tok_e[2*t+1];
  unsigned long long lt = (lane == 63) ? 0x7FFFFFFFFFFFFFFFull
                                       : ((1ull << lane) - 1ull);
  int r0 = 0, r1 = 0;
  #pragma unroll
  for (int e = 0; e < NE; e++) {
    unsigned long long m0 = __ballot(e1 == e);
    unsigned long long m1 = __ballot(e2 == e);
    if (e1 == e) r0 = __popcll(m0 & lt) + __popcll(m1 & lt);
    if (e2 == e) r1 = __popcll(m0 & lt) + (int)(e1 == e) + __popcll(m1 & lt);
    if (lane == 0) wcnt[wv][e] = __popcll(m0) + __popcll(m1);
  }
  __syncthreads();
  if (tid < NE) {
    int s = 0;
    #pragma unroll
    for (int w = 0; w < 4; w++) { woff[w][tid] = s; s += wcnt[w][tid]; }
    chunk_cnt[blockIdx.x*NE + tid] = s;
  }
  __syncthreads();
  rnk[2*t]   = woff[wv][e1] + r0;
  rnk[2*t+1] = woff[wv][e2] + r1;
}

// ---------------- scan: expert offsets, chunk offsets, tile descriptors -----
__global__ void k_scan(const int* __restrict__ chunk_cnt, int* __restrict__ offs,
    int* __restrict__ coff, int* __restrict__ d_e, int* __restrict__ d_r0,
    int* __restrict__ d_valid, int* __restrict__ ntiles) {
  if (threadIdx.x == 0 && blockIdx.x == 0) {
    int cnt[NE];
    for (int e = 0; e < NE; e++) {
      int s = 0;
      for (int c = 0; c < 8; c++) s += chunk_cnt[c*NE + e];
      cnt[e] = s;
    }
    int off = 0, nt2 = 0;
    for (int e = 0; e < NE; e++) {
      offs[e] = off;
      int s = off;
      for (int c = 0; c < 8; c++) { coff[c*NE + e] = s; s += chunk_cnt[c*NE + e]; }
      for (int r = 0; r < cnt[e]; r += 128) {
        d_e[nt2] = e; d_r0[nt2] = off + r;
        d_valid[nt2] = (cnt[e] - r < 128) ? (cnt[e] - r) : 128;
        nt2++;
      }
      off += cnt[e];
    }
    *ntiles = nt2;
  }
}

// ---------------- gather: xg[slot] = bf16(p * x[token]), no atomics ---------
__global__ __launch_bounds__(256) void k_gather(const float* __restrict__ x,
    const int* __restrict__ tok_e, const float* __restrict__ tok_p,
    const int* __restrict__ rnk, const int* __restrict__ coff,
    int* __restrict__ assign_token, ushort* __restrict__ xg) {
  int tid = threadIdx.x, lane = tid & 63;
  int t = blockIdx.x*4 + (tid >> 6);
  const float* xr = x + (size_t)t*DM;
  int chunk = t >> 8;
  #pragma unroll
  for (int j = 0; j < 2; j++) {
    int e = tok_e[2*t+j];
    float pp = tok_p[2*t+j];
    int slot = coff[chunk*NE + e] + rnk[2*t+j];
    if (lane == 0) assign_token[slot] = t;
    ushort* dst = xg + (size_t)slot*DM;
    #pragma unroll
    for (int it = 0; it < 2; it++) {
      int c = lane + it*64;
      float4 v0 = *(const float4*)(xr + c*8);
      float4 v1 = *(const float4*)(xr + c*8 + 4);
      uint4 o;
      o.x = (uint32_t)f2bf(v0.x*pp) | ((uint32_t)f2bf(v0.y*pp) << 16);
      o.y = (uint32_t)f2bf(v0.z*pp) | ((uint32_t)f2bf(v0.w*pp) << 16);
      o.z = (uint32_t)f2bf(v1.x*pp) | ((uint32_t)f2bf(v1.y*pp) << 16);
      o.w = (uint32_t)f2bf(v1.z*pp) | ((uint32_t)f2bf(v1.w*pp) << 16);
      *(uint4*)(dst + c*8) = o;
    }
  }
}

// ---------------- transpose: src [E][K][N] f32 -> dst [E][N][K] bf16 --------
__global__ __launch_bounds__(256) void k_transpose(const float* __restrict__ src,
    ushort* __restrict__ dst, int K, int N) {
  __shared__ ushort tl[64][68];
  int e = blockIdx.z;
  const float* s = src + (size_t)e*K*N;
  ushort* d = dst + (size_t)e*N*K;
  int n0 = blockIdx.x*64, k0 = blockIdx.y*64;
  int tid = threadIdx.x;
  int cx = tid & 15, ry = tid >> 4;
  #pragma unroll
  for (int p = 0; p < 4; p++) {
    int k = k0 + ry + p*16;
    float4 v = *(const float4*)(s + (size_t)k*N + n0 + cx*4);
    tl[cx*4+0][ry+p*16] = f2bf(v.x);
    tl[cx*4+1][ry+p*16] = f2bf(v.y);
    tl[cx*4+2][ry+p*16] = f2bf(v.z);
    tl[cx*4+3][ry+p*16] = f2bf(v.w);
  }
  __syncthreads();
  #pragma unroll
  for (int p = 0; p < 4; p++) {
    int n = ry + p*16;
    ushort* dp = d + (size_t)(n0+n)*K + k0 + cx*4;
    uint2 o;
    o.x = (uint32_t)tl[n][cx*4+0] | ((uint32_t)tl[n][cx*4+1] << 16);
    o.y = (uint32_t)tl[n][cx*4+2] | ((uint32_t)tl[n][cx*4+3] << 16);
    *(uint2*)dp = o;
  }
}

// ---- gate|up GEMM (m97 config): 128x128 tile, BK=32, 4 waves (2x2),
//      4x4 acc/wave (16 MFMA per wave per K-step), gload_lds + XOR swizzle ---
// writes RAW values to gu_raw [CAPROWS][4096]
__global__ __launch_bounds__(256) void k_gemm_gu(
    const ushort* __restrict__ Abuf, const ushort* __restrict__ Bbuf,
    ushort* __restrict__ gu_raw,
    const int* __restrict__ d_e, const int* __restrict__ d_r0,
    const int* __restrict__ d_valid, const int* __restrict__ ntiles) {
  if (blockIdx.y >= *ntiles) return;
  const int K = DM;
  const int e     = d_e[blockIdx.y];
  const int row0  = d_r0[blockIdx.y];
  const int valid = d_valid[blockIdx.y];
  const int n0 = blockIdx.x * 128;

  __shared__ __align__(16) ushort As[128*BK];  // 8KB
  __shared__ __align__(16) ushort Bs[128*BK];  // 8KB

  int tid = threadIdx.x;
  int lane = tid & 63;
  int wv = tid >> 6;          // 0..3
  int wm = wv >> 1, wn = wv & 1;

  const ushort* Ab = Abuf + (size_t)row0 * K;
  const ushort* Bb = Bbuf + ((size_t)e*4096 + n0) * K;

  // staging: phys row tid>>2, phys chunk tid&3; source fetches LOGICAL chunk
  // (tid&3) ^ ((tid>>3)&3) (inverse swizzle); dest linear per wave
  int sr  = tid >> 2;
  int sc8 = (((tid & 3) ^ ((tid >> 3) & 3))) * 8;
  const ushort* Ag0 = Ab + (size_t)sr*K + sc8;
  const ushort* Ag1 = Ab + (size_t)(sr+64)*K + sc8;
  const ushort* Bg0 = Bb + (size_t)sr*K + sc8;
  const ushort* Bg1 = Bb + (size_t)(sr+64)*K + sc8;
  ushort* Ad0 = As + wv*512;  ushort* Ad1 = As + 2048 + wv*512;
  ushort* Bd0 = Bs + wv*512;  ushort* Bd1 = Bs + 2048 + wv*512;

  f32x4 acc[4][4];
  f32x4 zz = {0.f, 0.f, 0.f, 0.f};
  #pragma unroll
  for (int mi = 0; mi < 4; mi++)
    #pragma unroll
    for (int ni = 0; ni < 4; ni++) acc[mi][ni] = zz;

  // read side: logical chunk lane>>4 at phys chunk (lane>>4)^((lane>>1)&3)
  int roff = (lane & 15)*BK + ((lane >> 4) ^ ((lane >> 1) & 3))*8;

  const int NK = K / BK;   // 32
  for (int kt = 0; kt < NK; kt++) {
    int ko = kt * BK;
    __syncthreads();
    GLOAD16(Ag0 + ko, Ad0); GLOAD16(Ag1 + ko, Ad1);
    GLOAD16(Bg0 + ko, Bd0); GLOAD16(Bg1 + ko, Bd1);
    __syncthreads();   // vmcnt(0) drain before barrier

    bf16x8 af[4], bfr[4];
    #pragma unroll
    for (int mi = 0; mi < 4; mi++)
      af[mi] = *(const bf16x8*)(As + (wm*64 + mi*16)*BK + roff);
    #pragma unroll
    for (int ni = 0; ni < 4; ni++)
      bfr[ni] = *(const bf16x8*)(Bs + (wn*64 + ni*16)*BK + roff);
    #pragma unroll
    for (int mi = 0; mi < 4; mi++)
      #pragma unroll
      for (int ni = 0; ni < 4; ni++)
        acc[mi][ni] = __builtin_amdgcn_mfma_f32_16x16x32_bf16(af[mi], bfr[ni], acc[mi][ni], 0, 0, 0);
  }

  #pragma unroll
  for (int mi = 0; mi < 4; mi++) {
    #pragma unroll
    for (int r = 0; r < 4; r++) {
      int row_l = wm*64 + mi*16 + (lane>>4)*4 + r;
      if (row_l < valid) {
        #pragma unroll
        for (int ni = 0; ni < 4; ni++) {
          int col = n0 + wn*64 + ni*16 + (lane&15);
          gu_raw[(size_t)(row0+row_l)*4096 + col] = f2bf(acc[mi][ni][r]);
        }
      }
    }
  }
}

// ---- combine: hid = silu(clip(gate)) * up, vectorized x8 -------------------
__global__ __launch_bounds__(256) void k_combine(const ushort* __restrict__ gu_raw,
    ushort* __restrict__ hid) {
  int i = blockIdx.x*256 + threadIdx.x;   // one 8-elem vec per thread
  int r  = i >> 8;                        // 2048/8 = 256 vecs per row
  int c8 = (i & 255) * 8;
  const ushort* g = gu_raw + (size_t)r*4096 + c8;
  const ushort* u = g + 2048;
  uint4 gv = *(const uint4*)g;
  uint4 uv = *(const uint4*)u;
  uint32_t gw[4] = {gv.x, gv.y, gv.z, gv.w};
  uint32_t uw[4] = {uv.x, uv.y, uv.z, uv.w};
  uint32_t ow[4];
  #pragma unroll
  for (int q = 0; q < 4; q++) {
    uint32_t o = 0;
    #pragma unroll
    for (int h = 0; h < 2; h++) {
      float gf = bf2f((ushort)(gw[q] >> (16*h)));
      float uf = bf2f((ushort)(uw[q] >> (16*h)));
      gf = fminf(fmaxf(gf, -10.f), 10.f);
      float sg = gf / (1.f + __expf(-gf));
      o |= ((uint32_t)f2bf(sg * uf)) << (16*h);
    }
    ow[q] = o;
  }
  *(uint4*)(hid + (size_t)r*2048 + c8) = make_uint4(ow[0], ow[1], ow[2], ow[3]);
}

// ---- down GEMM (m97 config): 128x128 tile, BK=32, 4 waves, K-split=2 -------
// out[token] += hid_tile[:, kz*1024 .. +1024] @ dnt[:, kz*1024 .. +1024]^T
__global__ __launch_bounds__(256) void k_gemm_dn(
    const ushort* __restrict__ Abuf, const ushort* __restrict__ Bbuf,
    float* __restrict__ out,
    const int* __restrict__ d_e, const int* __restrict__ d_r0,
    const int* __restrict__ d_valid, const int* __restrict__ ntiles,
    const int* __restrict__ assign_token) {
  if (blockIdx.y >= *ntiles) return;
  const int e     = d_e[blockIdx.y];
  const int row0  = d_r0[blockIdx.y];
  const int valid = d_valid[blockIdx.y];
  const int n0 = blockIdx.x * 128;
  const int kz = blockIdx.z;              // 0,1 K-split halves

  __shared__ __align__(16) ushort As[128*BK];  // 8KB
  __shared__ __align__(16) ushort Bs[128*BK];  // 8KB
  __shared__ int toks[128];

  int tid = threadIdx.x;
  int lane = tid & 63;
  int wv = tid >> 6;
  int wm = wv >> 1, wn = wv & 1;

  const ushort* Ab = Abuf + (size_t)row0 * DFF + kz*1024;
  const ushort* Bb = Bbuf + ((size_t)e*1024 + n0) * DFF + kz*1024;
  if (tid < 128) toks[tid] = assign_token[row0 + tid];

  int sr  = tid >> 2;
  int sc8 = (((tid & 3) ^ ((tid >> 3) & 3))) * 8;
  const ushort* Ag0 = Ab + (size_t)sr*DFF + sc8;
  const ushort* Ag1 = Ab + (size_t)(sr+64)*DFF + sc8;
  const ushort* Bg0 = Bb + (size_t)sr*DFF + sc8;
  const ushort* Bg1 = Bb + (size_t)(sr+64)*DFF + sc8;
  ushort* Ad0 = As + wv*512;  ushort* Ad1 = As + 2048 + wv*512;
  ushort* Bd0 = Bs + wv*512;  ushort* Bd1 = Bs + 2048 + wv*512;

  f32x4 acc[4][4];
  f32x4 zz = {0.f, 0.f, 0.f, 0.f};
  #pragma unroll
  for (int mi = 0; mi < 4; mi++)
    #pragma unroll
    for (int ni = 0; ni < 4; ni++) acc[mi][ni] = zz;

  int roff = (lane & 15)*BK + ((lane >> 4) ^ ((lane >> 1) & 3))*8;

  const int NK = 1024 / BK;   // 32 per half
  for (int kt = 0; kt < NK; kt++) {
    int ko = kt * BK;
    __syncthreads();
    GLOAD16(Ag0 + ko, Ad0); GLOAD16(Ag1 + ko, Ad1);
    GLOAD16(Bg0 + ko, Bd0); GLOAD16(Bg1 + ko, Bd1);
    __syncthreads();

    bf16x8 af[4], bfr[4];
    #pragma unroll
    for (int mi = 0; mi < 4; mi++)
      af[mi] = *(const bf16x8*)(As + (wm*64 + mi*16)*BK + roff);
    #pragma unroll
    for (int ni = 0; ni < 4; ni++)
      bfr[ni] = *(const bf16x8*)(Bs + (wn*64 + ni*16)*BK + roff);
    #pragma unroll
    for (int mi = 0; mi < 4; mi++)
      #pragma unroll
      for (int ni = 0; ni < 4; ni++)
        acc[mi][ni] = __builtin_amdgcn_mfma_f32_16x16x32_bf16(af[mi], bfr[ni], acc[mi][ni], 0, 0, 0);
  }

  #pragma unroll
  for (int mi = 0; mi < 4; mi++) {
    #pragma unroll
    for (int r = 0; r < 4; r++) {
      int row_l = wm*64 + mi*16 + (lane>>4)*4 + r;
      if (row_l < valid) {
        #pragma unroll
        for (int ni = 0; ni < 4; ni++) {
          int col = n0 + wn*64 + ni*16 + (lane&15);
          atomicAdd(out + (size_t)toks[row_l]*DM + col, acc[mi][ni][r]);
        }
      }
    }
  }
}

// ---------------- launch ----------------
extern "C" void kernel_launch(void* const* d_in, const int* in_sizes, int n_in,
                              void* d_out, int out_size, void* d_ws, size_t ws_size,
                              hipStream_t stream) {
  const float* x   = (const float*)d_in[0];
  const float* rw  = (const float*)d_in[1];
  const float* guw = (const float*)d_in[2];
  const float* dnw = (const float*)d_in[3];
  float* out = (float*)d_out;
  char* ws = (char*)d_ws;

  int* ctrl = (int*)ws;        // 2 KB control block
  int* ntl  = ctrl + 0;        // 1
  int* offs = ctrl + 8;        // 8
  int* de   = ctrl + 16;       // 64
  int* dr0  = ctrl + 80;       // 64
  int* dva  = ctrl + 144;      // 64
  int* ccnt = ctrl + 208;      // 64 chunk_cnt[8][8]
  int* coff = ctrl + 272;      // 64 coff[8][8]

  int*    tok_e  = (int*)  (ws + 2048);           // 4096 ints
  float*  tok_p  = (float*)(ws + 18432);          // 4096 f32
  int*    assign = (int*)  (ws + 34816);          // 4096 ints
  ushort* xg     = (ushort*)(ws + 51200);         // CAPROWS x 1024 bf16
  ushort* hid    = (ushort*)(ws + 8701952ull);    // CAPROWS x 2048 bf16
  int*    rnk    = (int*)   (ws + 8701952ull);    // aliases hid head: dead early
  ushort* guraw  = (ushort*)(ws + 26003456ull);   // CAPROWS x 4096 bf16
  ushort* gut    = (ushort*)(ws + 60606464ull);   // 8 x 4096 x 1024 bf16
  ushort* dnt    = (ushort*)(ws + 127715328ull);  // 8 x 1024 x 2048 bf16
  // total ws needed: 161,269,760 bytes (ws_size = 512 MiB per fill evidence)

  hipMemsetAsync(out, 0, (size_t)NT*DM*4, stream);

  k_router<<<NT/4, 256, 0, stream>>>(x, rw, tok_e, tok_p);
  k_count<<<NT/256, 256, 0, stream>>>(tok_e, rnk, ccnt);
  k_scan<<<1, 64, 0, stream>>>(ccnt, offs, coff, de, dr0, dva, ntl);
  k_gather<<<NT/4, 256, 0, stream>>>(x, tok_e, tok_p, rnk, coff, assign, xg);
  k_transpose<<<dim3(64, 16, 8), 256, 0, stream>>>(guw, gut, 1024, 4096);
  k_transpose<<<dim3(16, 32, 8), 256, 0, stream>>>(dnw, dnt, 2048, 1024);

  k_gemm_gu<<<dim3(32, MAXTILES), 256, 0, stream>>>(xg, gut, guraw, de, dr0, dva, ntl);
  k_combine<<<CAPROWS, 256, 0, stream>>>(guraw, hid);
  k_gemm_dn<<<dim3(8, MAXTILES, 2), 256, 0, stream>>>(hid, dnt, out, de, dr0, dva, ntl, assign);
}

// Round 11
// 380.602 us; speedup vs baseline: 1.1274x; 1.1274x over previous
//
#include <hip/hip_runtime.h>
#include <hip/hip_bf16.h>
#include <stdint.h>

#define NT 2048
#define DM 1024
#define DFF 2048
#define NE 8
#define NASSIGN (NT*2)
#define CAPROWS (NASSIGN+128)
#define MAXTILES 40

typedef __attribute__((ext_vector_type(4))) float f32x4;
typedef __attribute__((ext_vector_type(8))) short bf16x8;

// async global->LDS, 16B per lane; LDS dest = wave-uniform base + lane*16
#define GLOAD16(gptr, lptr) __builtin_amdgcn_global_load_lds( \
    (const __attribute__((address_space(1))) void*)(gptr), \
    (__attribute__((address_space(3))) void*)(lptr), 16, 0, 0)

__device__ __forceinline__ ushort f2bf(float f) {
  union { float f; uint32_t u; } v; v.f = f;
  uint32_t u = v.u;
  return (ushort)((u + 0x7FFFu + ((u >> 16) & 1u)) >> 16);
}

// ---------------- router: one wave per token (no atomics) ----------------
__global__ __launch_bounds__(256) void k_router(const float* __restrict__ x,
    const float* __restrict__ rw, int* __restrict__ tok_e, float* __restrict__ tok_p) {
  __shared__ float srw[NE*DM];
  int tid = threadIdx.x;
  #pragma unroll
  for (int i = 0; i < NE*DM/256; i++) srw[tid + i*256] = rw[tid + i*256];
  __syncthreads();
  int lane = tid & 63;
  int t = blockIdx.x*4 + (tid >> 6);
  const float* xr = x + (size_t)t*DM;
  float acc[NE];
  #pragma unroll
  for (int e = 0; e < NE; e++) acc[e] = 0.f;
  for (int i = lane; i < DM; i += 64) {
    float xv = xr[i];
    #pragma unroll
    for (int e = 0; e < NE; e++) acc[e] = fmaf(xv, srw[e*DM + i], acc[e]);
  }
  #pragma unroll
  for (int e = 0; e < NE; e++) {
    float v = acc[e];
    #pragma unroll
    for (int o = 32; o > 0; o >>= 1) v += __shfl_xor(v, o);
    acc[e] = v;
  }
  float mx = acc[0];
  #pragma unroll
  for (int e = 1; e < NE; e++) mx = fmaxf(mx, acc[e]);
  float p[NE]; float s = 0.f;
  #pragma unroll
  for (int e = 0; e < NE; e++) { p[e] = __expf(acc[e]-mx); s += p[e]; }
  int e1 = 0; float b1 = p[0];
  #pragma unroll
  for (int e = 1; e < NE; e++) if (p[e] > b1) { b1 = p[e]; e1 = e; }
  int e2 = -1; float b2 = -1.f;
  #pragma unroll
  for (int e = 0; e < NE; e++) if (e != e1 && p[e] > b2) { b2 = p[e]; e2 = e; }
  if (lane == 0) {
    tok_e[2*t] = e1; tok_e[2*t+1] = e2;
    float inv = 1.f/s;
    tok_p[2*t] = b1*inv; tok_p[2*t+1] = b2*inv;
  }
}

// ---------------- count: deterministic within-chunk ranks, no atomics -------
__global__ __launch_bounds__(256) void k_count(const int* __restrict__ tok_e,
    int* __restrict__ rnk, int* __restrict__ chunk_cnt) {
  __shared__ int wcnt[4][NE];
  __shared__ int woff[4][NE];
  int tid = threadIdx.x, lane = tid & 63, wv = tid >> 6;
  int t = blockIdx.x*256 + tid;
  int e1 = tok_e[2*t], e2 = tok_e[2*t+1];
  unsigned long long lt = (lane == 63) ? 0x7FFFFFFFFFFFFFFFull
                                       : ((1ull << lane) - 1ull);
  int r0 = 0, r1 = 0;
  #pragma unroll
  for (int e = 0; e < NE; e++) {
    unsigned long long m0 = __ballot(e1 == e);
    unsigned long long m1 = __ballot(e2 == e);
    if (e1 == e) r0 = __popcll(m0 & lt) + __popcll(m1 & lt);
    if (e2 == e) r1 = __popcll(m0 & lt) + (int)(e1 == e) + __popcll(m1 & lt);
    if (lane == 0) wcnt[wv][e] = __popcll(m0) + __popcll(m1);
  }
  __syncthreads();
  if (tid < NE) {
    int s = 0;
    #pragma unroll
    for (int w = 0; w < 4; w++) { woff[w][tid] = s; s += wcnt[w][tid]; }
    chunk_cnt[blockIdx.x*NE + tid] = s;
  }
  __syncthreads();
  rnk[2*t]   = woff[wv][e1] + r0;
  rnk[2*t+1] = woff[wv][e2] + r1;
}

// ---------------- scan: expert offsets, chunk offsets, tile descriptors -----
__global__ void k_scan(const int* __restrict__ chunk_cnt, int* __restrict__ offs,
    int* __restrict__ coff, int* __restrict__ d_e, int* __restrict__ d_r0,
    int* __restrict__ d_valid, int* __restrict__ ntiles) {
  if (threadIdx.x == 0 && blockIdx.x == 0) {
    int cnt[NE];
    for (int e = 0; e < NE; e++) {
      int s = 0;
      for (int c = 0; c < 8; c++) s += chunk_cnt[c*NE + e];
      cnt[e] = s;
    }
    int off = 0, nt2 = 0;
    for (int e = 0; e < NE; e++) {
      offs[e] = off;
      int s = off;
      for (int c = 0; c < 8; c++) { coff[c*NE + e] = s; s += chunk_cnt[c*NE + e]; }
      for (int r = 0; r < cnt[e]; r += 128) {
        d_e[nt2] = e; d_r0[nt2] = off + r;
        d_valid[nt2] = (cnt[e] - r < 128) ? (cnt[e] - r) : 128;
        nt2++;
      }
      off += cnt[e];
    }
    *ntiles = nt2;
  }
}

// ---------------- gather: xg[slot] = bf16(p * x[token]), no atomics ---------
__global__ __launch_bounds__(256) void k_gather(const float* __restrict__ x,
    const int* __restrict__ tok_e, const float* __restrict__ tok_p,
    const int* __restrict__ rnk, const int* __restrict__ coff,
    int* __restrict__ assign_token, ushort* __restrict__ xg) {
  int tid = threadIdx.x, lane = tid & 63;
  int t = blockIdx.x*4 + (tid >> 6);
  const float* xr = x + (size_t)t*DM;
  int chunk = t >> 8;
  #pragma unroll
  for (int j = 0; j < 2; j++) {
    int e = tok_e[2*t+j];
    float pp = tok_p[2*t+j];
    int slot = coff[chunk*NE + e] + rnk[2*t+j];
    if (lane == 0) assign_token[slot] = t;
    ushort* dst = xg + (size_t)slot*DM;
    #pragma unroll
    for (int it = 0; it < 2; it++) {
      int c = lane + it*64;
      float4 v0 = *(const float4*)(xr + c*8);
      float4 v1 = *(const float4*)(xr + c*8 + 4);
      uint4 o;
      o.x = (uint32_t)f2bf(v0.x*pp) | ((uint32_t)f2bf(v0.y*pp) << 16);
      o.y = (uint32_t)f2bf(v0.z*pp) | ((uint32_t)f2bf(v0.w*pp) << 16);
      o.z = (uint32_t)f2bf(v1.x*pp) | ((uint32_t)f2bf(v1.y*pp) << 16);
      o.w = (uint32_t)f2bf(v1.z*pp) | ((uint32_t)f2bf(v1.w*pp) << 16);
      *(uint4*)(dst + c*8) = o;
    }
  }
}

// ---------------- transpose: src [E][K][N] f32 -> dst [E][N][K] bf16 --------
__global__ __launch_bounds__(256) void k_transpose(const float* __restrict__ src,
    ushort* __restrict__ dst, int K, int N) {
  __shared__ ushort tl[64][68];
  int e = blockIdx.z;
  const float* s = src + (size_t)e*K*N;
  ushort* d = dst + (size_t)e*N*K;
  int n0 = blockIdx.x*64, k0 = blockIdx.y*64;
  int tid = threadIdx.x;
  int cx = tid & 15, ry = tid >> 4;
  #pragma unroll
  for (int p = 0; p < 4; p++) {
    int k = k0 + ry + p*16;
    float4 v = *(const float4*)(s + (size_t)k*N + n0 + cx*4);
    tl[cx*4+0][ry+p*16] = f2bf(v.x);
    tl[cx*4+1][ry+p*16] = f2bf(v.y);
    tl[cx*4+2][ry+p*16] = f2bf(v.z);
    tl[cx*4+3][ry+p*16] = f2bf(v.w);
  }
  __syncthreads();
  #pragma unroll
  for (int p = 0; p < 4; p++) {
    int n = ry + p*16;
    ushort* dp = d + (size_t)(n0+n)*K + k0 + cx*4;
    uint2 o;
    o.x = (uint32_t)tl[n][cx*4+0] | ((uint32_t)tl[n][cx*4+1] << 16);
    o.y = (uint32_t)tl[n][cx*4+2] | ((uint32_t)tl[n][cx*4+3] << 16);
    *(uint2*)dp = o;
  }
}

// ---- fused gate+up GEMM: 128(M)x64(N)x{gate,up}, BK=64, 8 waves (4Mx2N),
//      each wave 32x32 of BOTH panels; 2-barrier loop (16 steps),
//      gload_lds + XOR swizzle p = c ^ (row&7) on 128B rows ------------------
__global__ __launch_bounds__(512) void k_gemm_gu(
    const ushort* __restrict__ Abuf, const ushort* __restrict__ Bbuf,
    ushort* __restrict__ hidden,
    const int* __restrict__ d_e, const int* __restrict__ d_r0,
    const int* __restrict__ d_valid, const int* __restrict__ ntiles) {
  if (blockIdx.y >= *ntiles) return;
  const int K = DM;
  const int e     = d_e[blockIdx.y];
  const int row0  = d_r0[blockIdx.y];
  const int valid = d_valid[blockIdx.y];
  const int n0 = blockIdx.x * 64;

  __shared__ __align__(16) ushort As[128*64];  // 16KB  A rows 0..127, 64 k
  __shared__ __align__(16) ushort Bs[128*64];  // 16KB  rows 0..63 gate, 64..127 up

  int tid = threadIdx.x;
  int lane = tid & 63;
  int wv = tid >> 6;          // 0..7
  int wm = wv >> 1;           // 0..3 -> M rows wm*32..+31
  int wn = wv & 1;            // 0..1 -> N cols wn*32..+31

  const ushort* Ab  = Abuf + (size_t)row0 * K;
  const ushort* Bgb = Bbuf + ((size_t)e*4096 + n0) * K;
  const ushort* Bub = Bbuf + ((size_t)e*4096 + 2048 + n0) * K;

  // staging: thread t -> phys row t>>3 (0..63 per issue), phys chunk t&7;
  // source fetches LOGICAL chunk (t&7) ^ ((t>>3)&7)  (inverse swizzle)
  int sr  = tid >> 3;
  int sc8 = (((tid & 7) ^ ((tid >> 3) & 7))) * 8;
  const ushort* Ag0 = Ab  + (size_t)sr*K + sc8;          // rows 0..63
  const ushort* Ag1 = Ab  + (size_t)(sr+64)*K + sc8;     // rows 64..127
  const ushort* Gg  = Bgb + (size_t)sr*K + sc8;          // gate rows 0..63
  const ushort* Ug  = Bub + (size_t)sr*K + sc8;          // up rows 0..63

  f32x4 ag[2][2], au[2][2];
  f32x4 zz = {0.f, 0.f, 0.f, 0.f};
  #pragma unroll
  for (int mi = 0; mi < 2; mi++)
    #pragma unroll
    for (int ni = 0; ni < 2; ni++) { ag[mi][ni] = zz; au[mi][ni] = zz; }

  // read side: logical chunk (h*4 + lane>>4) of row r at phys chunk
  // (h*4 + lane>>4) ^ (r&7); since 4^g==4+g for g<4, h=1 offset = roff ^ 32
  int roff = (lane & 15)*64 + (((lane >> 4) ^ (lane & 7)))*8;

  const int NK = K / 64;   // 16
  for (int kt = 0; kt < NK; kt++) {
    int ko = kt * 64;
    __syncthreads();
    GLOAD16(Ag0 + ko, As + wv*512);
    GLOAD16(Ag1 + ko, As + 4096 + wv*512);
    GLOAD16(Gg  + ko, Bs + wv*512);
    GLOAD16(Ug  + ko, Bs + 4096 + wv*512);
    __syncthreads();   // compiler drains vmcnt(0) before s_barrier

    #pragma unroll
    for (int h = 0; h < 2; h++) {
      int ro = roff ^ (h * 32);
      bf16x8 af[2], bgf[2], buf[2];
      #pragma unroll
      for (int mi = 0; mi < 2; mi++)
        af[mi] = *(const bf16x8*)(As + (wm*32 + mi*16)*64 + ro);
      #pragma unroll
      for (int ni = 0; ni < 2; ni++) {
        bgf[ni] = *(const bf16x8*)(Bs + (wn*32 + ni*16)*64 + ro);
        buf[ni] = *(const bf16x8*)(Bs + (64 + wn*32 + ni*16)*64 + ro);
      }
      #pragma unroll
      for (int mi = 0; mi < 2; mi++)
        #pragma unroll
        for (int ni = 0; ni < 2; ni++) {
          ag[mi][ni] = __builtin_amdgcn_mfma_f32_16x16x32_bf16(af[mi], bgf[ni], ag[mi][ni], 0, 0, 0);
          au[mi][ni] = __builtin_amdgcn_mfma_f32_16x16x32_bf16(af[mi], buf[ni], au[mi][ni], 0, 0, 0);
        }
    }
  }

  #pragma unroll
  for (int mi = 0; mi < 2; mi++) {
    #pragma unroll
    for (int r = 0; r < 4; r++) {
      int row_l = wm*32 + mi*16 + (lane>>4)*4 + r;
      if (row_l < valid) {
        #pragma unroll
        for (int ni = 0; ni < 2; ni++) {
          int col = n0 + wn*32 + ni*16 + (lane&15);
          float g = ag[mi][ni][r];
          g = fminf(fmaxf(g, -10.f), 10.f);
          float sg = g / (1.f + __expf(-g));
          float h = sg * au[mi][ni][r];
          hidden[(size_t)(row0+row_l)*DFF + col] = f2bf(h);
        }
      }
    }
  }
}

// ---- down GEMM: 128(M)x64(N), BK=64, 8 waves (4Mx2N, 32x32 each),
//      2-barrier loop (32 steps), gload_lds + XOR swizzle --------------------
// out[token] += hidden_tile @ dnt
__global__ __launch_bounds__(512) void k_gemm_dn(
    const ushort* __restrict__ Abuf, const ushort* __restrict__ Bbuf,
    float* __restrict__ out,
    const int* __restrict__ d_e, const int* __restrict__ d_r0,
    const int* __restrict__ d_valid, const int* __restrict__ ntiles,
    const int* __restrict__ assign_token) {
  if (blockIdx.y >= *ntiles) return;
  const int K = DFF;
  const int e     = d_e[blockIdx.y];
  const int row0  = d_r0[blockIdx.y];
  const int valid = d_valid[blockIdx.y];
  const int n0 = blockIdx.x * 64;

  __shared__ __align__(16) ushort As[128*64];  // 16KB
  __shared__ __align__(16) ushort Bs[ 64*64];  //  8KB
  __shared__ int toks[128];

  int tid = threadIdx.x;
  int lane = tid & 63;
  int wv = tid >> 6;
  int wm = wv >> 1;           // 0..3
  int wn = wv & 1;            // 0..1

  const ushort* Ab = Abuf + (size_t)row0 * K;
  const ushort* Bb = Bbuf + ((size_t)e*1024 + n0) * K;
  if (tid < 128) toks[tid] = assign_token[row0 + tid];

  int sr  = tid >> 3;
  int sc8 = (((tid & 7) ^ ((tid >> 3) & 7))) * 8;
  const ushort* Ag0 = Ab + (size_t)sr*K + sc8;
  const ushort* Ag1 = Ab + (size_t)(sr+64)*K + sc8;
  const ushort* Bg  = Bb + (size_t)sr*K + sc8;

  f32x4 acc[2][2];
  f32x4 zz = {0.f, 0.f, 0.f, 0.f};
  #pragma unroll
  for (int mi = 0; mi < 2; mi++)
    #pragma unroll
    for (int ni = 0; ni < 2; ni++) acc[mi][ni] = zz;

  int roff = (lane & 15)*64 + (((lane >> 4) ^ (lane & 7)))*8;

  const int NK = K / 64;   // 32
  for (int kt = 0; kt < NK; kt++) {
    int ko = kt * 64;
    __syncthreads();
    GLOAD16(Ag0 + ko, As + wv*512);
    GLOAD16(Ag1 + ko, As + 4096 + wv*512);
    GLOAD16(Bg  + ko, Bs + wv*512);
    __syncthreads();

    #pragma unroll
    for (int h = 0; h < 2; h++) {
      int ro = roff ^ (h * 32);
      bf16x8 af[2], bf2[2];
      #pragma unroll
      for (int mi = 0; mi < 2; mi++)
        af[mi] = *(const bf16x8*)(As + (wm*32 + mi*16)*64 + ro);
      #pragma unroll
      for (int ni = 0; ni < 2; ni++)
        bf2[ni] = *(const bf16x8*)(Bs + (wn*32 + ni*16)*64 + ro);
      #pragma unroll
      for (int mi = 0; mi < 2; mi++)
        #pragma unroll
        for (int ni = 0; ni < 2; ni++)
          acc[mi][ni] = __builtin_amdgcn_mfma_f32_16x16x32_bf16(af[mi], bf2[ni], acc[mi][ni], 0, 0, 0);
    }
  }

  #pragma unroll
  for (int mi = 0; mi < 2; mi++) {
    #pragma unroll
    for (int r = 0; r < 4; r++) {
      int row_l = wm*32 + mi*16 + (lane>>4)*4 + r;
      if (row_l < valid) {
        #pragma unroll
        for (int ni = 0; ni < 2; ni++) {
          int col = n0 + wn*32 + ni*16 + (lane&15);
          atomicAdd(out + (size_t)toks[row_l]*DM + col, acc[mi][ni][r]);
        }
      }
    }
  }
}

// ---------------- launch ----------------
extern "C" void kernel_launch(void* const* d_in, const int* in_sizes, int n_in,
                              void* d_out, int out_size, void* d_ws, size_t ws_size,
                              hipStream_t stream) {
  const float* x   = (const float*)d_in[0];
  const float* rw  = (const float*)d_in[1];
  const float* guw = (const float*)d_in[2];
  const float* dnw = (const float*)d_in[3];
  float* out = (float*)d_out;
  char* ws = (char*)d_ws;

  int* ctrl = (int*)ws;        // 2 KB control block
  int* ntl  = ctrl + 0;        // 1
  int* offs = ctrl + 8;        // 8
  int* de   = ctrl + 16;       // 64
  int* dr0  = ctrl + 80;       // 64
  int* dva  = ctrl + 144;      // 64
  int* ccnt = ctrl + 208;      // 64 chunk_cnt[8][8]
  int* coff = ctrl + 272;      // 64 coff[8][8]

  int*    tok_e  = (int*)  (ws + 2048);          // 4096 ints
  float*  tok_p  = (float*)(ws + 18432);         // 4096 f32
  int*    assign = (int*)  (ws + 34816);         // 4096 ints
  ushort* xg     = (ushort*)(ws + 51200);        // CAPROWS x 1024 bf16
  ushort* hid    = (ushort*)(ws + 8701952ull);   // CAPROWS x 2048 bf16
  int*    rnk    = (int*)   (ws + 8701952ull);   // aliases hid head: dead before gemm_gu
  ushort* gut    = (ushort*)(ws + 26003456ull);  // 8 x 4096 x 1024 bf16
  ushort* dnt    = (ushort*)(ws + 93112320ull);  // 8 x 1024 x 2048 bf16
  // total ws needed: 126,666,752 bytes

  hipMemsetAsync(out, 0, (size_t)NT*DM*4, stream);

  k_router<<<NT/4, 256, 0, stream>>>(x, rw, tok_e, tok_p);
  k_count<<<NT/256, 256, 0, stream>>>(tok_e, rnk, ccnt);
  k_scan<<<1, 64, 0, stream>>>(ccnt, offs, coff, de, dr0, dva, ntl);
  k_gather<<<NT/4, 256, 0, stream>>>(x, tok_e, tok_p, rnk, coff, assign, xg);
  k_transpose<<<dim3(64, 16, 8), 256, 0, stream>>>(guw, gut, 1024, 4096);
  k_transpose<<<dim3(16, 32, 8), 256, 0, stream>>>(dnw, dnt, 2048, 1024);

  k_gemm_gu<<<dim3(32, MAXTILES), 512, 0, stream>>>(xg, gut, hid, de, dr0, dva, ntl);
  k_gemm_dn<<<dim3(16, MAXTILES), 512, 0, stream>>>(hid, dnt, out, de, dr0, dva, ntl, assign);
}